// Round 4
// baseline (337.554 us; speedup 1.0000x reference)
//
#include <hip/hip_runtime.h>
#include <hip/hip_bf16.h>

typedef __bf16 bf16_t;
typedef __bf16 bf16x8 __attribute__((ext_vector_type(8)));
typedef float f32x4 __attribute__((ext_vector_type(4)));

// ---------------------------------------------------------------------------
// fp32 src[R][C] -> bf16 dst[C][R]   (workspace use: 2 MB total)
// ---------------------------------------------------------------------------
__global__ __launch_bounds__(256) void transpose_cast_kernel(
    const float* __restrict__ src, bf16_t* __restrict__ dst, int R, int C)
{
    __shared__ float tile[32][33];
    const int bx = blockIdx.x;  // C/32
    const int by = blockIdx.y;  // R/32
    const int t  = threadIdx.x;
    const int i0 = t >> 5;      // 0..7
    const int j  = t & 31;
#pragma unroll
    for (int p = 0; p < 4; ++p) {
        int i = i0 + p * 8;
        tile[i][j] = src[(long)(by * 32 + i) * C + bx * 32 + j];
    }
    __syncthreads();
#pragma unroll
    for (int p = 0; p < 4; ++p) {
        int i = i0 + p * 8;
        dst[(long)(bx * 32 + i) * R + by * 32 + j] = (bf16_t)tile[j][i];
    }
}

// ---------------------------------------------------------------------------
// Fully fused window attention: one block per window (b,n), 256 threads.
// Phase 1 (per head h): QKV = x_win[64,512] @ wT-cols  -> lQ/lK/lVT (LDS)
// Phase 2 (per head h): S=QK^T, softmax, O=PV          -> lAO (LDS, proj layout)
// Phase 3: out_rows = lAO[64,512] @ pT^T + bias        -> scattered global rows
//
// Raw-reshape mapping (derived, checked): O(h,w,d) of window (b,n) lands at
// proj-input row m = b*4096 + h*512 + n*8 + (w>>3), channel c = (w&7)*64 + d.
// lAO is indexed [row' = h*8 + (w>>3)][c], so phase 3 is a plain GEMM.
// x, bias, out are fp32 in global memory; compute is bf16 MFMA / fp32 acc.
// ---------------------------------------------------------------------------
__global__ __launch_bounds__(256) void fused_win_attn(
    const float*  __restrict__ x,     // [512 windows][64][512] fp32
    const bf16_t* __restrict__ wT,    // [1536][512]  (= w_qkv^T, bf16)
    const bf16_t* __restrict__ pT,    // [512][512]   (= w_proj^T, bf16)
    const float*  __restrict__ bias,  // [512] fp32
    float* __restrict__ out)          // [32768][512] fp32
{
    // LDS arenas (phase-disjoint unions, barriers guard every reuse):
    __shared__ bf16_t lAO[64 * 520];     // persistent attention output (66.5 KB)
    __shared__ bf16_t arena1[64 * 72];   // lXc (k-loop) / lP (attention)
    __shared__ bf16_t arena2[192 * 72];  // lW (k-loops) / lQ+lK (attention)
    __shared__ bf16_t lVT[64 * 72];      // V transposed [d][k]

    bf16_t* const lXc = arena1;
    bf16_t* const lP  = arena1;
    bf16_t* const lW  = arena2;
    bf16_t* const lQ  = arena2;
    bf16_t* const lK  = arena2 + 64 * 72;

    const int wid = blockIdx.x;          // b*64 + n
    const int bb  = wid >> 6;
    const int nw  = wid & 63;
    const float* xw = x + (long)wid * 64 * 512;

    const int t    = threadIdx.x;
    const int wave = t >> 6;
    const int lane = t & 63;
    const int lr   = lane & 15;
    const int q    = lane >> 4;

    const float scale = 0.125f;          // dh^-0.5

    for (int h = 0; h < 8; ++h) {
        // ---- QKV GEMM: M=64 (tokens), N=192 (Q|K|V x 64), K=512 ----
        f32x4 acc[12];
#pragma unroll
        for (int j = 0; j < 12; ++j) acc[j] = (f32x4)0.0f;

        for (int kc = 0; kc < 8; ++kc) {
            const int k0 = kc * 64;
            // stage x chunk [64][64] fp32 -> bf16: 512 vec8, 2 per thread
#pragma unroll
            for (int p = 0; p < 2; ++p) {
                const int v = t + p * 256;
                const int r = v >> 3, c = (v & 7) * 8;
                const float* rp = xw + (long)r * 512 + k0 + c;
                f32x4 f0 = *(const f32x4*)rp;
                f32x4 f1 = *(const f32x4*)(rp + 4);
                bf16x8 o;
                o[0] = (bf16_t)f0[0]; o[1] = (bf16_t)f0[1];
                o[2] = (bf16_t)f0[2]; o[3] = (bf16_t)f0[3];
                o[4] = (bf16_t)f1[0]; o[5] = (bf16_t)f1[1];
                o[6] = (bf16_t)f1[2]; o[7] = (bf16_t)f1[3];
                *(bf16x8*)&lXc[r * 72 + c] = o;
            }
            // stage wT chunk [192][64]: rows g*512 + h*64 + i of wT (bf16)
#pragma unroll
            for (int p = 0; p < 6; ++p) {
                const int v = t + p * 256;
                const int nr = v >> 3, c = (v & 7) * 8;
                const int g = nr >> 6, i = nr & 63;
                *(bf16x8*)&lW[nr * 72 + c] =
                    *(const bf16x8*)(wT + (long)(g * 512 + h * 64 + i) * 512 + k0 + c);
            }
            __syncthreads();
#pragma unroll
            for (int ks = 0; ks < 64; ks += 32) {
                bf16x8 af = *(const bf16x8*)&lXc[(wave * 16 + lr) * 72 + ks + q * 8];
#pragma unroll
                for (int j = 0; j < 12; ++j) {
                    bf16x8 bf = *(const bf16x8*)&lW[(j * 16 + lr) * 72 + ks + q * 8];
                    acc[j] = __builtin_amdgcn_mfma_f32_16x16x32_bf16(af, bf, acc[j], 0, 0, 0);
                }
            }
            __syncthreads();
        }

        // scatter QKV accumulators to LDS (C/D layout: col=lr, row=q*4+reg)
#pragma unroll
        for (int j = 0; j < 4; ++j)
#pragma unroll
            for (int reg = 0; reg < 4; ++reg) {
                const int row = wave * 16 + q * 4 + reg;
                lQ[row * 72 + j * 16 + lr] = (bf16_t)acc[j][reg];
            }
#pragma unroll
        for (int j = 4; j < 8; ++j)
#pragma unroll
            for (int reg = 0; reg < 4; ++reg) {
                const int row = wave * 16 + q * 4 + reg;
                lK[row * 72 + (j - 4) * 16 + lr] = (bf16_t)acc[j][reg];
            }
#pragma unroll
        for (int j = 8; j < 12; ++j)
#pragma unroll
            for (int reg = 0; reg < 4; ++reg) {
                const int row = wave * 16 + q * 4 + reg;
                lVT[((j - 8) * 16 + lr) * 72 + row] = (bf16_t)acc[j][reg];
            }
        __syncthreads();   // all QKV in LDS

        // ---- S = Q K^T (wave handles query rows wave*16..+15) ----
        f32x4 s[4];
#pragma unroll
        for (int j = 0; j < 4; ++j) s[j] = (f32x4)0.0f;
#pragma unroll
        for (int ks = 0; ks < 64; ks += 32) {
            bf16x8 aq = *(const bf16x8*)&lQ[(wave * 16 + lr) * 72 + ks + q * 8];
#pragma unroll
            for (int j = 0; j < 4; ++j) {
                bf16x8 bk = *(const bf16x8*)&lK[(j * 16 + lr) * 72 + ks + q * 8];
                s[j] = __builtin_amdgcn_mfma_f32_16x16x32_bf16(aq, bk, s[j], 0, 0, 0);
            }
        }

        // ---- softmax: row = wave*16 + q*4 + reg spans 4 regs x 16 lanes(lr) ----
#pragma unroll
        for (int reg = 0; reg < 4; ++reg) {
            float m = fmaxf(fmaxf(s[0][reg], s[1][reg]), fmaxf(s[2][reg], s[3][reg]));
#pragma unroll
            for (int d = 1; d < 16; d <<= 1) m = fmaxf(m, __shfl_xor(m, d));
            float p[4];
            float sum = 0.0f;
#pragma unroll
            for (int j = 0; j < 4; ++j) {
                p[j] = __expf((s[j][reg] - m) * scale);
                sum += p[j];
            }
#pragma unroll
            for (int d = 1; d < 16; d <<= 1) sum += __shfl_xor(sum, d);
            const float inv = 1.0f / sum;
            const int row = wave * 16 + q * 4 + reg;
#pragma unroll
            for (int j = 0; j < 4; ++j)
                lP[row * 72 + j * 16 + lr] = (bf16_t)(p[j] * inv);
        }
        // lP rows are wave-private; no barrier needed before PV.

        // ---- O = P V ----
        f32x4 o[4];
#pragma unroll
        for (int d4 = 0; d4 < 4; ++d4) o[d4] = (f32x4)0.0f;
#pragma unroll
        for (int ks = 0; ks < 64; ks += 32) {
            bf16x8 ap = *(const bf16x8*)&lP[(wave * 16 + lr) * 72 + ks + q * 8];
#pragma unroll
            for (int d4 = 0; d4 < 4; ++d4) {
                bf16x8 bv = *(const bf16x8*)&lVT[(d4 * 16 + lr) * 72 + ks + q * 8];
                o[d4] = __builtin_amdgcn_mfma_f32_16x16x32_bf16(ap, bv, o[d4], 0, 0, 0);
            }
        }

        // ---- store O into lAO in proj-matrix coordinates ----
#pragma unroll
        for (int d4 = 0; d4 < 4; ++d4)
#pragma unroll
            for (int reg = 0; reg < 4; ++reg) {
                const int wr = wave * 16 + q * 4 + reg;
                lAO[(h * 8 + (wr >> 3)) * 520 + (wr & 7) * 64 + d4 * 16 + lr] =
                    (bf16_t)o[d4][reg];
            }
        __syncthreads();   // end of head: protects arena1/arena2 reuse
    }

    // ---- proj GEMM: [64 rows'] x [512 cols], K=512, A = lAO (LDS) ----
    for (int ns = 0; ns < 4; ++ns) {
        f32x4 pacc[8];
#pragma unroll
        for (int j = 0; j < 8; ++j) pacc[j] = (f32x4)0.0f;
        for (int kc = 0; kc < 8; ++kc) {
            const int k0 = kc * 64;
            // stage pT rows [ns*128 .. +128) x [k0 .. +64)
#pragma unroll
            for (int p = 0; p < 4; ++p) {
                const int v = t + p * 256;
                const int r = v >> 3, c = (v & 7) * 8;
                *(bf16x8*)&lW[r * 72 + c] =
                    *(const bf16x8*)(pT + (long)(ns * 128 + r) * 512 + k0 + c);
            }
            __syncthreads();
#pragma unroll
            for (int ks = 0; ks < 64; ks += 32) {
                bf16x8 af = *(const bf16x8*)&lAO[(wave * 16 + lr) * 520 + k0 + ks + q * 8];
#pragma unroll
                for (int j = 0; j < 8; ++j) {
                    bf16x8 bf = *(const bf16x8*)&lW[(j * 16 + lr) * 72 + ks + q * 8];
                    pacc[j] = __builtin_amdgcn_mfma_f32_16x16x32_bf16(af, bf, pacc[j], 0, 0, 0);
                }
            }
            __syncthreads();
        }
        // epilogue: row' -> global row m = bb*4096 + (row'>>3)*512 + nw*8 + (row'&7)
#pragma unroll
        for (int j = 0; j < 8; ++j) {
            const int col = ns * 128 + j * 16 + lr;
            const float bv = bias[col];
#pragma unroll
            for (int reg = 0; reg < 4; ++reg) {
                const int rp = wave * 16 + q * 4 + reg;
                const long m = (long)bb * 4096 + (long)(rp >> 3) * 512 + nw * 8 + (rp & 7);
                out[m * 512 + col] = pacc[j][reg] + bv;
            }
        }
    }
}

// ---------------------------------------------------------------------------
extern "C" void kernel_launch(void* const* d_in, const int* in_sizes, int n_in,
                              void* d_out, int out_size, void* d_ws, size_t ws_size,
                              hipStream_t stream)
{
    (void)in_sizes; (void)n_in; (void)out_size; (void)ws_size;
    const float* x     = (const float*)d_in[0];  // [8,64,64,512] fp32
    const float* wqkv  = (const float*)d_in[1];  // [512,1536] fp32
    const float* wproj = (const float*)d_in[2];  // [512,512] fp32
    const float* bproj = (const float*)d_in[3];  // [512] fp32
    float* out = (float*)d_out;                  // [8,64,64,512] fp32

    // workspace: only the two bf16 weight transposes (2 MB total)
    bf16_t* wT = (bf16_t*)d_ws;                  // [1536][512]
    bf16_t* pT = wT + (size_t)1536 * 512;        // [512][512]

    transpose_cast_kernel<<<dim3(48, 16), 256, 0, stream>>>(wqkv, wT, 512, 1536);
    transpose_cast_kernel<<<dim3(16, 16), 256, 0, stream>>>(wproj, pT, 512, 512);

    fused_win_attn<<<512, 256, 0, stream>>>(x, wT, pT, bproj, out);
}

// Round 5
// 254.697 us; speedup vs baseline: 1.3253x; 1.3253x over previous
//
#include <hip/hip_runtime.h>
#include <hip/hip_bf16.h>

typedef __bf16 bf16_t;
typedef __bf16 bf16x8 __attribute__((ext_vector_type(8)));
typedef float f32x4 __attribute__((ext_vector_type(4)));

// ---------------------------------------------------------------------------
// fp32 src[R][C] -> bf16 dst[C][R]
// ---------------------------------------------------------------------------
__global__ __launch_bounds__(256) void transpose_cast_kernel(
    const float* __restrict__ src, bf16_t* __restrict__ dst, int R, int C)
{
    __shared__ float tile[32][33];
    const int bx = blockIdx.x;  // C/32
    const int by = blockIdx.y;  // R/32
    const int t  = threadIdx.x;
    const int i0 = t >> 5;      // 0..7
    const int j  = t & 31;
#pragma unroll
    for (int p = 0; p < 4; ++p) {
        int i = i0 + p * 8;
        tile[i][j] = src[(long)(by * 32 + i) * C + bx * 32 + j];
    }
    __syncthreads();
#pragma unroll
    for (int p = 0; p < 4; ++p) {
        int i = i0 + p * 8;
        dst[(long)(bx * 32 + i) * R + by * 32 + j] = (bf16_t)tile[j][i];
    }
}

// ---------------------------------------------------------------------------
// QKV + window attention: one block per window (b,n), 256 threads, 46 KB LDS
// (3 blocks/CU). Per head: K-loop QKV GEMM -> lQ/lK/lVT; S=QK^T; softmax;
// O=PV; O written to global ao (bf16) directly in proj-matrix row layout:
//   ao row m = b*4096 + h*512 + n*8 + (w>>3), channel c = (w&7)*64 + d.
// ---------------------------------------------------------------------------
__global__ __launch_bounds__(256) void qkv_attn_kernel(
    const float*  __restrict__ x,     // [512 windows][64][512] fp32
    const bf16_t* __restrict__ wT,    // [1536][512]  (= w_qkv^T, bf16)
    bf16_t* __restrict__ ao)          // [32768][512] bf16, proj layout
{
    __shared__ bf16_t arena1[64 * 72];   // lXc (k-loop) / lP (attention)
    __shared__ bf16_t arena2[192 * 72];  // lW (k-loop) / lQ+lK (attention)
    __shared__ bf16_t lVT[64 * 72];      // V transposed [d][k]

    bf16_t* const lXc = arena1;
    bf16_t* const lP  = arena1;
    bf16_t* const lW  = arena2;
    bf16_t* const lQ  = arena2;
    bf16_t* const lK  = arena2 + 64 * 72;

    const int wid = blockIdx.x;          // b*64 + n
    const int bb  = wid >> 6;
    const int nw  = wid & 63;
    const float* xw = x + (long)wid * 64 * 512;

    const int t    = threadIdx.x;
    const int wave = t >> 6;
    const int lane = t & 63;
    const int lr   = lane & 15;
    const int q    = lane >> 4;

    const float scale = 0.125f;          // dh^-0.5

    for (int h = 0; h < 8; ++h) {
        // ---- QKV GEMM: M=64 (tokens), N=192 (Q|K|V x 64), K=512 ----
        f32x4 acc[12];
#pragma unroll
        for (int j = 0; j < 12; ++j) acc[j] = (f32x4)0.0f;

        for (int kc = 0; kc < 8; ++kc) {
            const int k0 = kc * 64;
            // stage x chunk [64][64] fp32 -> bf16: 512 vec8, 2 per thread
#pragma unroll
            for (int p = 0; p < 2; ++p) {
                const int v = t + p * 256;
                const int r = v >> 3, c = (v & 7) * 8;
                const float* rp = xw + (long)r * 512 + k0 + c;
                f32x4 f0 = *(const f32x4*)rp;
                f32x4 f1 = *(const f32x4*)(rp + 4);
                bf16x8 o;
                o[0] = (bf16_t)f0[0]; o[1] = (bf16_t)f0[1];
                o[2] = (bf16_t)f0[2]; o[3] = (bf16_t)f0[3];
                o[4] = (bf16_t)f1[0]; o[5] = (bf16_t)f1[1];
                o[6] = (bf16_t)f1[2]; o[7] = (bf16_t)f1[3];
                *(bf16x8*)&lXc[r * 72 + c] = o;
            }
            // stage wT chunk [192][64]: rows g*512 + h*64 + i of wT (bf16)
#pragma unroll
            for (int p = 0; p < 6; ++p) {
                const int v = t + p * 256;
                const int nr = v >> 3, c = (v & 7) * 8;
                const int g = nr >> 6, i = nr & 63;
                *(bf16x8*)&lW[nr * 72 + c] =
                    *(const bf16x8*)(wT + (long)(g * 512 + h * 64 + i) * 512 + k0 + c);
            }
            __syncthreads();
#pragma unroll
            for (int ks = 0; ks < 64; ks += 32) {
                bf16x8 af = *(const bf16x8*)&lXc[(wave * 16 + lr) * 72 + ks + q * 8];
#pragma unroll
                for (int j = 0; j < 12; ++j) {
                    bf16x8 bf = *(const bf16x8*)&lW[(j * 16 + lr) * 72 + ks + q * 8];
                    acc[j] = __builtin_amdgcn_mfma_f32_16x16x32_bf16(af, bf, acc[j], 0, 0, 0);
                }
            }
            __syncthreads();
        }

        // scatter QKV accumulators to LDS (C/D layout: col=lr, row=q*4+reg)
#pragma unroll
        for (int j = 0; j < 4; ++j)
#pragma unroll
            for (int reg = 0; reg < 4; ++reg) {
                const int row = wave * 16 + q * 4 + reg;
                lQ[row * 72 + j * 16 + lr] = (bf16_t)acc[j][reg];
            }
#pragma unroll
        for (int j = 4; j < 8; ++j)
#pragma unroll
            for (int reg = 0; reg < 4; ++reg) {
                const int row = wave * 16 + q * 4 + reg;
                lK[row * 72 + (j - 4) * 16 + lr] = (bf16_t)acc[j][reg];
            }
#pragma unroll
        for (int j = 8; j < 12; ++j)
#pragma unroll
            for (int reg = 0; reg < 4; ++reg) {
                const int row = wave * 16 + q * 4 + reg;
                lVT[((j - 8) * 16 + lr) * 72 + row] = (bf16_t)acc[j][reg];
            }
        __syncthreads();   // all QKV in LDS

        // ---- S = Q K^T (wave handles query rows wave*16..+15) ----
        f32x4 s[4];
#pragma unroll
        for (int j = 0; j < 4; ++j) s[j] = (f32x4)0.0f;
#pragma unroll
        for (int ks = 0; ks < 64; ks += 32) {
            bf16x8 aq = *(const bf16x8*)&lQ[(wave * 16 + lr) * 72 + ks + q * 8];
#pragma unroll
            for (int j = 0; j < 4; ++j) {
                bf16x8 bk = *(const bf16x8*)&lK[(j * 16 + lr) * 72 + ks + q * 8];
                s[j] = __builtin_amdgcn_mfma_f32_16x16x32_bf16(aq, bk, s[j], 0, 0, 0);
            }
        }

        // ---- softmax: row = wave*16 + q*4 + reg spans 4 regs x 16 lanes(lr) ----
#pragma unroll
        for (int reg = 0; reg < 4; ++reg) {
            float m = fmaxf(fmaxf(s[0][reg], s[1][reg]), fmaxf(s[2][reg], s[3][reg]));
#pragma unroll
            for (int d = 1; d < 16; d <<= 1) m = fmaxf(m, __shfl_xor(m, d));
            float p[4];
            float sum = 0.0f;
#pragma unroll
            for (int j = 0; j < 4; ++j) {
                p[j] = __expf((s[j][reg] - m) * scale);
                sum += p[j];
            }
#pragma unroll
            for (int d = 1; d < 16; d <<= 1) sum += __shfl_xor(sum, d);
            const float inv = 1.0f / sum;
            const int row = wave * 16 + q * 4 + reg;
#pragma unroll
            for (int j = 0; j < 4; ++j)
                lP[row * 72 + j * 16 + lr] = (bf16_t)(p[j] * inv);
        }
        // lP rows are wave-private; no barrier needed before PV.

        // ---- O = P V ----
        f32x4 o[4];
#pragma unroll
        for (int d4 = 0; d4 < 4; ++d4) o[d4] = (f32x4)0.0f;
#pragma unroll
        for (int ks = 0; ks < 64; ks += 32) {
            bf16x8 ap = *(const bf16x8*)&lP[(wave * 16 + lr) * 72 + ks + q * 8];
#pragma unroll
            for (int d4 = 0; d4 < 4; ++d4) {
                bf16x8 bv = *(const bf16x8*)&lVT[(d4 * 16 + lr) * 72 + ks + q * 8];
                o[d4] = __builtin_amdgcn_mfma_f32_16x16x32_bf16(ap, bv, o[d4], 0, 0, 0);
            }
        }

        // ---- write O to global ao in proj-matrix coordinates ----
        bf16_t* aop = ao + ((long)bb * 4096 + (long)h * 512 + nw * 8) * 512;
#pragma unroll
        for (int d4 = 0; d4 < 4; ++d4)
#pragma unroll
            for (int reg = 0; reg < 4; ++reg) {
                const int wr = wave * 16 + q * 4 + reg;
                aop[(long)(wr >> 3) * 512 + (wr & 7) * 64 + d4 * 16 + lr] =
                    (bf16_t)o[d4][reg];
            }
        __syncthreads();   // end of head: protects arena1/arena2/lVT reuse
    }
}

// ---------------------------------------------------------------------------
// out[M,N] = ao[M,K] @ pT[N,K]^T + bias, bf16 in / fp32 out, fp32 accumulate.
// 128x128 tile, BK=64, 4 waves (2x2), 4x4 MFMA 16x16x32 per wave.
// M=32768, N=512, K=512.
// ---------------------------------------------------------------------------
#define LDP 72

__global__ __launch_bounds__(256) void gemm2_kernel(
    const bf16_t* __restrict__ A,    // [M,K] = ao
    const bf16_t* __restrict__ Bt,   // [N,K] = pT
    const float*  __restrict__ bias, // [N]
    float* __restrict__ C,           // [M,N]
    int M, int N, int K)
{
    __shared__ bf16_t lA[128 * LDP];
    __shared__ bf16_t lB[128 * LDP];

    const int tid  = threadIdx.x;
    const int wave = tid >> 6;
    const int lane = tid & 63;
    const int wm   = wave >> 1;
    const int wn   = wave & 1;
    const int lr   = lane & 15;
    const int q    = lane >> 4;

    const long arow0 = (long)blockIdx.y * 128;
    const long brow0 = (long)blockIdx.x * 128;

    f32x4 acc[4][4];
#pragma unroll
    for (int i = 0; i < 4; ++i)
#pragma unroll
        for (int j = 0; j < 4; ++j) acc[i][j] = (f32x4)0.0f;

    const int srow = tid >> 3;        // 0..31
    const int scol = (tid & 7) * 8;   // 0..56

    const int nk = K / 64;
    for (int kt = 0; kt < nk; ++kt) {
        const bf16_t* Ag = A + arow0 * K + kt * 64;
        const bf16_t* Bg = Bt + brow0 * K + kt * 64;
        bf16x8 av[4], bv[4];
#pragma unroll
        for (int p = 0; p < 4; ++p) {
            const int r = srow + p * 32;
            av[p] = *(const bf16x8*)(Ag + (long)r * K + scol);
            bv[p] = *(const bf16x8*)(Bg + (long)r * K + scol);
        }
#pragma unroll
        for (int p = 0; p < 4; ++p) {
            const int r = srow + p * 32;
            *(bf16x8*)&lA[r * LDP + scol] = av[p];
            *(bf16x8*)&lB[r * LDP + scol] = bv[p];
        }
        __syncthreads();
#pragma unroll
        for (int ks = 0; ks < 64; ks += 32) {
            bf16x8 af[4], bf[4];
#pragma unroll
            for (int i = 0; i < 4; ++i)
                af[i] = *(const bf16x8*)&lA[(wm * 64 + i * 16 + lr) * LDP + ks + q * 8];
#pragma unroll
            for (int j = 0; j < 4; ++j)
                bf[j] = *(const bf16x8*)&lB[(wn * 64 + j * 16 + lr) * LDP + ks + q * 8];
#pragma unroll
            for (int i = 0; i < 4; ++i)
#pragma unroll
                for (int j = 0; j < 4; ++j)
                    acc[i][j] = __builtin_amdgcn_mfma_f32_16x16x32_bf16(
                        af[i], bf[j], acc[i][j], 0, 0, 0);
        }
        __syncthreads();
    }

    // epilogue: C/D layout col=lane&15, row=(lane>>4)*4+reg
#pragma unroll
    for (int i = 0; i < 4; ++i) {
        const long r = arow0 + wm * 64 + i * 16 + q * 4;
#pragma unroll
        for (int j = 0; j < 4; ++j) {
            const long c = brow0 + wn * 64 + j * 16 + lr;
            const float bv2 = bias[c];
#pragma unroll
            for (int reg = 0; reg < 4; ++reg) {
                C[(r + reg) * N + c] = acc[i][j][reg] + bv2;
            }
        }
    }
}

// ---------------------------------------------------------------------------
extern "C" void kernel_launch(void* const* d_in, const int* in_sizes, int n_in,
                              void* d_out, int out_size, void* d_ws, size_t ws_size,
                              hipStream_t stream)
{
    (void)in_sizes; (void)n_in; (void)out_size; (void)ws_size;
    const float* x     = (const float*)d_in[0];  // [8,64,64,512] fp32
    const float* wqkv  = (const float*)d_in[1];  // [512,1536] fp32
    const float* wproj = (const float*)d_in[2];  // [512,512] fp32
    const float* bproj = (const float*)d_in[3];  // [512] fp32
    float* out = (float*)d_out;                  // [8,64,64,512] fp32

    // workspace: wT 1.5 MB + pT 0.5 MB + ao 32 MB = 34 MB
    bf16_t* wT = (bf16_t*)d_ws;                  // [1536][512]
    bf16_t* pT = wT + (size_t)1536 * 512;        // [512][512]
    bf16_t* ao = pT + (size_t)512 * 512;         // [32768][512] proj layout

    transpose_cast_kernel<<<dim3(48, 16), 256, 0, stream>>>(wqkv, wT, 512, 1536);
    transpose_cast_kernel<<<dim3(16, 16), 256, 0, stream>>>(wproj, pT, 512, 512);

    qkv_attn_kernel<<<512, 256, 0, stream>>>(x, wT, ao);

    gemm2_kernel<<<dim3(4, 256), 256, 0, stream>>>(
        ao, pT, bproj, out, 32768, 512, 512);
}

// Round 6
// 228.942 us; speedup vs baseline: 1.4744x; 1.1125x over previous
//
#include <hip/hip_runtime.h>
#include <hip/hip_bf16.h>

typedef __bf16 bf16_t;
typedef __bf16 bf16x8 __attribute__((ext_vector_type(8)));
typedef float f32x4 __attribute__((ext_vector_type(4)));

// ---------------------------------------------------------------------------
// fp32 src[R][C] -> bf16 dst[C][R]
// ---------------------------------------------------------------------------
__global__ __launch_bounds__(256) void transpose_cast_kernel(
    const float* __restrict__ src, bf16_t* __restrict__ dst, int R, int C)
{
    __shared__ float tile[32][33];
    const int bx = blockIdx.x;  // C/32
    const int by = blockIdx.y;  // R/32
    const int t  = threadIdx.x;
    const int i0 = t >> 5;      // 0..7
    const int j  = t & 31;
#pragma unroll
    for (int p = 0; p < 4; ++p) {
        int i = i0 + p * 8;
        tile[i][j] = src[(long)(by * 32 + i) * C + bx * 32 + j];
    }
    __syncthreads();
#pragma unroll
    for (int p = 0; p < 4; ++p) {
        int i = i0 + p * 8;
        dst[(long)(bx * 32 + i) * R + by * 32 + j] = (bf16_t)tile[j][i];
    }
}

// ---------------------------------------------------------------------------
// QKV + window attention: one block per (window, head), 4096 blocks, 256 thr,
// 36.9 KB LDS -> 4 blocks/CU (16 waves). XCD swizzle: a window's 8 head-blocks
// land on one XCD (x fetched ~once/XCD; wT L2-resident).
// Per block: K-loop QKV GEMM (M=64 tokens, N=192, K=512) -> lQ/lK/lVT;
// S=QK^T; softmax; O=PV; O -> global ao (bf16) in proj-matrix row layout:
//   ao row m = b*4096 + h*512 + n*8 + (w>>3), channel c = (w&7)*64 + d.
// ---------------------------------------------------------------------------
__global__ __launch_bounds__(256) void qkv_attn_kernel(
    const float*  __restrict__ x,     // [512 windows][64][512] fp32
    const bf16_t* __restrict__ wT,    // [1536][512]  (= w_qkv^T, bf16)
    bf16_t* __restrict__ ao)          // [32768][512] bf16, proj layout
{
    __shared__ bf16_t arena1[64 * 72];   // lXc (k-loop) / lP (attention)
    __shared__ bf16_t arena2[192 * 72];  // lW (k-loop) / lQ+lK+lVT (attention)

    bf16_t* const lXc = arena1;
    bf16_t* const lP  = arena1;
    bf16_t* const lW  = arena2;
    bf16_t* const lQ  = arena2;
    bf16_t* const lK  = arena2 + 64 * 72;
    bf16_t* const lVT = arena2 + 128 * 72;  // V transposed [d][k]

    // XCD swizzle: dispatch round-robins id%8 across XCDs; keep a window's
    // 8 head-blocks on one XCD and adjacent windows together.
    const int id  = blockIdx.x;       // 0..4095
    const int xcd = id & 7;
    const int s   = id >> 3;          // 0..511
    const int wid = xcd * 64 + (s >> 3);  // b*64 + n
    const int h   = s & 7;

    const int bb  = wid >> 6;
    const int nw  = wid & 63;
    const float* xw = x + (long)wid * 64 * 512;

    const int t    = threadIdx.x;
    const int wave = t >> 6;
    const int lane = t & 63;
    const int lr   = lane & 15;
    const int q    = lane >> 4;

    const float scale = 0.125f;          // dh^-0.5

    // ---- QKV GEMM: M=64 (tokens), N=192 (Q|K|V x 64), K=512 ----
    f32x4 acc[12];
#pragma unroll
    for (int j = 0; j < 12; ++j) acc[j] = (f32x4)0.0f;

    for (int kc = 0; kc < 8; ++kc) {
        const int k0 = kc * 64;
        // stage x chunk [64][64] fp32 -> bf16: 512 vec8, 2 per thread
#pragma unroll
        for (int p = 0; p < 2; ++p) {
            const int v = t + p * 256;
            const int r = v >> 3, c = (v & 7) * 8;
            const float* rp = xw + (long)r * 512 + k0 + c;
            f32x4 f0 = *(const f32x4*)rp;
            f32x4 f1 = *(const f32x4*)(rp + 4);
            bf16x8 o;
            o[0] = (bf16_t)f0[0]; o[1] = (bf16_t)f0[1];
            o[2] = (bf16_t)f0[2]; o[3] = (bf16_t)f0[3];
            o[4] = (bf16_t)f1[0]; o[5] = (bf16_t)f1[1];
            o[6] = (bf16_t)f1[2]; o[7] = (bf16_t)f1[3];
            *(bf16x8*)&lXc[r * 72 + c] = o;
        }
        // stage wT chunk [192][64]: rows g*512 + h*64 + i of wT (bf16)
#pragma unroll
        for (int p = 0; p < 6; ++p) {
            const int v = t + p * 256;
            const int nr = v >> 3, c = (v & 7) * 8;
            const int g = nr >> 6, i = nr & 63;
            *(bf16x8*)&lW[nr * 72 + c] =
                *(const bf16x8*)(wT + (long)(g * 512 + h * 64 + i) * 512 + k0 + c);
        }
        __syncthreads();
#pragma unroll
        for (int ks = 0; ks < 64; ks += 32) {
            bf16x8 af = *(const bf16x8*)&lXc[(wave * 16 + lr) * 72 + ks + q * 8];
#pragma unroll
            for (int j = 0; j < 12; ++j) {
                bf16x8 bf = *(const bf16x8*)&lW[(j * 16 + lr) * 72 + ks + q * 8];
                acc[j] = __builtin_amdgcn_mfma_f32_16x16x32_bf16(af, bf, acc[j], 0, 0, 0);
            }
        }
        __syncthreads();   // also guards arena2 reuse (lW -> lQ/lK/lVT)
    }

    // scatter QKV accumulators to LDS (C/D layout: col=lr, row=q*4+reg)
#pragma unroll
    for (int j = 0; j < 4; ++j)
#pragma unroll
        for (int reg = 0; reg < 4; ++reg) {
            const int row = wave * 16 + q * 4 + reg;
            lQ[row * 72 + j * 16 + lr] = (bf16_t)acc[j][reg];
        }
#pragma unroll
    for (int j = 4; j < 8; ++j)
#pragma unroll
        for (int reg = 0; reg < 4; ++reg) {
            const int row = wave * 16 + q * 4 + reg;
            lK[row * 72 + (j - 4) * 16 + lr] = (bf16_t)acc[j][reg];
        }
#pragma unroll
    for (int j = 8; j < 12; ++j)
#pragma unroll
        for (int reg = 0; reg < 4; ++reg) {
            const int row = wave * 16 + q * 4 + reg;
            lVT[((j - 8) * 16 + lr) * 72 + row] = (bf16_t)acc[j][reg];
        }
    __syncthreads();   // all QKV in LDS

    // ---- S = Q K^T (wave handles query rows wave*16..+15) ----
    f32x4 sAcc[4];
#pragma unroll
    for (int j = 0; j < 4; ++j) sAcc[j] = (f32x4)0.0f;
#pragma unroll
    for (int ks = 0; ks < 64; ks += 32) {
        bf16x8 aq = *(const bf16x8*)&lQ[(wave * 16 + lr) * 72 + ks + q * 8];
#pragma unroll
        for (int j = 0; j < 4; ++j) {
            bf16x8 bk = *(const bf16x8*)&lK[(j * 16 + lr) * 72 + ks + q * 8];
            sAcc[j] = __builtin_amdgcn_mfma_f32_16x16x32_bf16(aq, bk, sAcc[j], 0, 0, 0);
        }
    }

    // ---- softmax: row = wave*16 + q*4 + reg spans 4 regs x 16 lanes(lr) ----
#pragma unroll
    for (int reg = 0; reg < 4; ++reg) {
        float m = fmaxf(fmaxf(sAcc[0][reg], sAcc[1][reg]),
                        fmaxf(sAcc[2][reg], sAcc[3][reg]));
#pragma unroll
        for (int d = 1; d < 16; d <<= 1) m = fmaxf(m, __shfl_xor(m, d));
        float p[4];
        float sum = 0.0f;
#pragma unroll
        for (int j = 0; j < 4; ++j) {
            p[j] = __expf((sAcc[j][reg] - m) * scale);
            sum += p[j];
        }
#pragma unroll
        for (int d = 1; d < 16; d <<= 1) sum += __shfl_xor(sum, d);
        const float inv = 1.0f / sum;
        const int row = wave * 16 + q * 4 + reg;
#pragma unroll
        for (int j = 0; j < 4; ++j)
            lP[row * 72 + j * 16 + lr] = (bf16_t)(p[j] * inv);
    }
    // lP rows are wave-private; no barrier needed before PV.

    // ---- O = P V ----
    f32x4 o[4];
#pragma unroll
    for (int d4 = 0; d4 < 4; ++d4) o[d4] = (f32x4)0.0f;
#pragma unroll
    for (int ks = 0; ks < 64; ks += 32) {
        bf16x8 ap = *(const bf16x8*)&lP[(wave * 16 + lr) * 72 + ks + q * 8];
#pragma unroll
        for (int d4 = 0; d4 < 4; ++d4) {
            bf16x8 bv = *(const bf16x8*)&lVT[(d4 * 16 + lr) * 72 + ks + q * 8];
            o[d4] = __builtin_amdgcn_mfma_f32_16x16x32_bf16(ap, bv, o[d4], 0, 0, 0);
        }
    }

    // ---- write O to global ao in proj-matrix coordinates ----
    bf16_t* aop = ao + ((long)bb * 4096 + (long)h * 512 + nw * 8) * 512;
#pragma unroll
    for (int d4 = 0; d4 < 4; ++d4)
#pragma unroll
        for (int reg = 0; reg < 4; ++reg) {
            const int wr = wave * 16 + q * 4 + reg;
            aop[(long)(wr >> 3) * 512 + (wr & 7) * 64 + d4 * 16 + lr] =
                (bf16_t)o[d4][reg];
        }
}

// ---------------------------------------------------------------------------
// out[M,N] = ao[M,K] @ pT[N,K]^T + bias, bf16 in / fp32 out, fp32 accumulate.
// 128x128 tile, BK=64, 4 waves (2x2), 4x4 MFMA 16x16x32 per wave.
// 1D grid of 1024 with XCD swizzle: the 4 bn-blocks sharing an A row-tile
// land on one XCD, and each XCD covers a contiguous 32-tile bm range
// (per-XCD A working set ~4.2 MB ~= L2) -> A HBM-fetched ~once.
// ---------------------------------------------------------------------------
#define LDP 72

__global__ __launch_bounds__(256) void gemm2_kernel(
    const bf16_t* __restrict__ A,    // [M,K] = ao
    const bf16_t* __restrict__ Bt,   // [N,K] = pT
    const float*  __restrict__ bias, // [N]
    float* __restrict__ C,           // [M,N]
    int M, int N, int K)
{
    __shared__ bf16_t lA[128 * LDP];
    __shared__ bf16_t lB[128 * LDP];

    const int tid  = threadIdx.x;
    const int wave = tid >> 6;
    const int lane = tid & 63;
    const int wm   = wave >> 1;
    const int wn   = wave & 1;
    const int lr   = lane & 15;
    const int q    = lane >> 4;

    // swizzle: id -> (bm, bn) with same-bm group on one XCD
    const int id  = blockIdx.x;       // 0..1023
    const int xcd = id & 7;
    const int s   = id >> 3;          // 0..127
    const int bm  = xcd * 32 + (s >> 2);
    const int bn  = s & 3;

    const long arow0 = (long)bm * 128;
    const long brow0 = (long)bn * 128;

    f32x4 acc[4][4];
#pragma unroll
    for (int i = 0; i < 4; ++i)
#pragma unroll
        for (int j = 0; j < 4; ++j) acc[i][j] = (f32x4)0.0f;

    const int srow = tid >> 3;        // 0..31
    const int scol = (tid & 7) * 8;   // 0..56

    const int nk = K / 64;
    for (int kt = 0; kt < nk; ++kt) {
        const bf16_t* Ag = A + arow0 * K + kt * 64;
        const bf16_t* Bg = Bt + brow0 * K + kt * 64;
        bf16x8 av[4], bv[4];
#pragma unroll
        for (int p = 0; p < 4; ++p) {
            const int r = srow + p * 32;
            av[p] = *(const bf16x8*)(Ag + (long)r * K + scol);
            bv[p] = *(const bf16x8*)(Bg + (long)r * K + scol);
        }
#pragma unroll
        for (int p = 0; p < 4; ++p) {
            const int r = srow + p * 32;
            *(bf16x8*)&lA[r * LDP + scol] = av[p];
            *(bf16x8*)&lB[r * LDP + scol] = bv[p];
        }
        __syncthreads();
#pragma unroll
        for (int ks = 0; ks < 64; ks += 32) {
            bf16x8 af[4], bf[4];
#pragma unroll
            for (int i = 0; i < 4; ++i)
                af[i] = *(const bf16x8*)&lA[(wm * 64 + i * 16 + lr) * LDP + ks + q * 8];
#pragma unroll
            for (int j = 0; j < 4; ++j)
                bf[j] = *(const bf16x8*)&lB[(wn * 64 + j * 16 + lr) * LDP + ks + q * 8];
#pragma unroll
            for (int i = 0; i < 4; ++i)
#pragma unroll
                for (int j = 0; j < 4; ++j)
                    acc[i][j] = __builtin_amdgcn_mfma_f32_16x16x32_bf16(
                        af[i], bf[j], acc[i][j], 0, 0, 0);
        }
        __syncthreads();
    }

    // epilogue: C/D layout col=lane&15, row=(lane>>4)*4+reg
#pragma unroll
    for (int i = 0; i < 4; ++i) {
        const long r = arow0 + wm * 64 + i * 16 + q * 4;
#pragma unroll
        for (int j = 0; j < 4; ++j) {
            const long c = brow0 + wn * 64 + j * 16 + lr;
            const float bv2 = bias[c];
#pragma unroll
            for (int reg = 0; reg < 4; ++reg) {
                C[(r + reg) * N + c] = acc[i][j][reg] + bv2;
            }
        }
    }
}

// ---------------------------------------------------------------------------
extern "C" void kernel_launch(void* const* d_in, const int* in_sizes, int n_in,
                              void* d_out, int out_size, void* d_ws, size_t ws_size,
                              hipStream_t stream)
{
    (void)in_sizes; (void)n_in; (void)out_size; (void)ws_size;
    const float* x     = (const float*)d_in[0];  // [8,64,64,512] fp32
    const float* wqkv  = (const float*)d_in[1];  // [512,1536] fp32
    const float* wproj = (const float*)d_in[2];  // [512,512] fp32
    const float* bproj = (const float*)d_in[3];  // [512] fp32
    float* out = (float*)d_out;                  // [8,64,64,512] fp32

    // workspace: wT 1.5 MB + pT 0.5 MB + ao 32 MB = 34 MB
    bf16_t* wT = (bf16_t*)d_ws;                  // [1536][512]
    bf16_t* pT = wT + (size_t)1536 * 512;        // [512][512]
    bf16_t* ao = pT + (size_t)512 * 512;         // [32768][512] proj layout

    transpose_cast_kernel<<<dim3(48, 16), 256, 0, stream>>>(wqkv, wT, 512, 1536);
    transpose_cast_kernel<<<dim3(16, 16), 256, 0, stream>>>(wproj, pT, 512, 512);

    qkv_attn_kernel<<<4096, 256, 0, stream>>>(x, wT, ao);

    gemm2_kernel<<<1024, 256, 0, stream>>>(
        ao, pT, bproj, out, 32768, 512, 512);
}